// Round 2
// baseline (178.260 us; speedup 1.0000x reference)
//
#include <hip/hip_runtime.h>

#define RES 128
#define FEAT 16
#define NQ 1000000
#define NBUCK (128 * 128)   // bucket key = (cx<<7) | cy

__device__ __forceinline__ void fma4(float4& a, float w, const float4& f) {
    a.x = fmaf(w, f.x, a.x);
    a.y = fmaf(w, f.y, a.y);
    a.z = fmaf(w, f.z, a.z);
    a.w = fmaf(w, f.w, a.w);
}

__device__ __forceinline__ int cell_coord(float v) {
    int c = (int)floorf(v * 127.0f);
    return min(max(c, 0), RES - 2);
}

// ---- Pass 1: histogram of bucket keys -------------------------------------
__global__ __launch_bounds__(256) void hist_kernel(
    const float* __restrict__ xyz, unsigned int* __restrict__ hist)
{
    int q = blockIdx.x * blockDim.x + threadIdx.x;
    if (q >= NQ) return;
    int cx = cell_coord(xyz[3 * q + 0]);
    int cy = cell_coord(xyz[3 * q + 1]);
    atomicAdd(&hist[(cx << 7) | cy], 1u);
}

// ---- Pass 2: exclusive scan over 16384 counters (single block) ------------
__global__ __launch_bounds__(1024) void scan_kernel(unsigned int* __restrict__ hist)
{
    __shared__ unsigned int partial[1024];
    int t = threadIdx.x;
    unsigned int vals[16];
    unsigned int sum = 0;
#pragma unroll
    for (int i = 0; i < 16; ++i) { vals[i] = hist[t * 16 + i]; sum += vals[i]; }
    partial[t] = sum;
    __syncthreads();
    for (int off = 1; off < 1024; off <<= 1) {
        unsigned int v = (t >= off) ? partial[t - off] : 0u;
        __syncthreads();
        partial[t] += v;
        __syncthreads();
    }
    unsigned int excl = (t == 0) ? 0u : partial[t - 1];
#pragma unroll
    for (int i = 0; i < 16; ++i) { unsigned int v = vals[i]; hist[t * 16 + i] = excl; excl += v; }
}

// ---- Pass 3: scatter queries into bucket order ----------------------------
__global__ __launch_bounds__(256) void scatter_kernel(
    const float* __restrict__ xyz, unsigned int* __restrict__ cursor,
    float4* __restrict__ sorted)
{
    int q = blockIdx.x * blockDim.x + threadIdx.x;
    if (q >= NQ) return;
    float x = xyz[3 * q + 0];
    float y = xyz[3 * q + 1];
    float z = xyz[3 * q + 2];
    int cx = cell_coord(x);
    int cy = cell_coord(y);
    unsigned int pos = atomicAdd(&cursor[(cx << 7) | cy], 1u);
    sorted[pos] = make_float4(x, y, z, __int_as_float(q));
}

// ---- Pass 4: interpolate in sorted order ----------------------------------
__global__ __launch_bounds__(256) void interp_sorted_kernel(
    const float4* __restrict__ sorted,
    const float* __restrict__ field,
    float* __restrict__ out)
{
    // bijective XCD-aware swizzle: each XCD gets a contiguous chunk of the
    // sorted (spatially ordered) query array -> contiguous cx-slab per L2.
    int nwg = gridDim.x;
    int qn = nwg >> 3, r = nwg & 7;
    int xcd = blockIdx.x & 7, i = blockIdx.x >> 3;
    int wg = (xcd < r ? xcd * (qn + 1) : r * (qn + 1) + (xcd - r) * qn) + i;

    int q = wg * blockDim.x + threadIdx.x;
    if (q >= NQ) return;

    float4 s = sorted[q];
    float x = s.x, y = s.y, z = s.z;
    int oidx = __float_as_int(s.w);

    const float scale = 127.0f;
    const float h = 1.0f / 127.0f;

    int cx = cell_coord(x);
    int cy = cell_coord(y);
    int cz = cell_coord(z);

    float tx = (x - (float)cx * h) * scale;
    float ty = (y - (float)cy * h) * scale;
    float tz = (z - (float)cz * h) * scale;

    float wx0 = 1.0f - tx, wx1 = tx;
    float wy0 = 1.0f - ty, wy1 = ty;
    float wz0 = 1.0f - tz, wz1 = tz;

    float w[8] = {
        wx0 * wy0 * wz0, wx0 * wy0 * wz1,
        wx0 * wy1 * wz0, wx0 * wy1 * wz1,
        wx1 * wy0 * wz0, wx1 * wy0 * wz1,
        wx1 * wy1 * wz0, wx1 * wy1 * wz1
    };

    long long base = ((long long)cx * RES + cy) * RES + cz;
    const long long R2 = (long long)RES * RES;
    const long long offs[8] = { 0, 1, RES, RES + 1, R2, R2 + 1, R2 + RES, R2 + RES + 1 };

    float4 acc0 = make_float4(0.f, 0.f, 0.f, 0.f);
    float4 acc1 = acc0, acc2 = acc0, acc3 = acc0;

#pragma unroll
    for (int c = 0; c < 8; ++c) {
        const float4* p = (const float4*)(field + (base + offs[c]) * FEAT);
        float4 f0 = p[0];
        float4 f1 = p[1];
        float4 f2 = p[2];
        float4 f3 = p[3];
        float wc = w[c];
        fma4(acc0, wc, f0);
        fma4(acc1, wc, f1);
        fma4(acc2, wc, f2);
        fma4(acc3, wc, f3);
    }

    float4* o = (float4*)(out + (long long)oidx * FEAT);
    o[0] = acc0;
    o[1] = acc1;
    o[2] = acc2;
    o[3] = acc3;
}

// ---- Fallback (round-1 direct kernel) -------------------------------------
__global__ __launch_bounds__(256) void tetra_interp_kernel(
    const float* __restrict__ xyz,
    const float* __restrict__ field,
    float* __restrict__ out)
{
    int q = blockIdx.x * blockDim.x + threadIdx.x;
    if (q >= NQ) return;

    float x = xyz[q * 3 + 0];
    float y = xyz[q * 3 + 1];
    float z = xyz[q * 3 + 2];

    const float scale = 127.0f;
    const float h = 1.0f / 127.0f;

    int cx = cell_coord(x);
    int cy = cell_coord(y);
    int cz = cell_coord(z);

    float tx = (x - (float)cx * h) * scale;
    float ty = (y - (float)cy * h) * scale;
    float tz = (z - (float)cz * h) * scale;

    float wx0 = 1.0f - tx, wx1 = tx;
    float wy0 = 1.0f - ty, wy1 = ty;
    float wz0 = 1.0f - tz, wz1 = tz;

    float w[8] = {
        wx0 * wy0 * wz0, wx0 * wy0 * wz1,
        wx0 * wy1 * wz0, wx0 * wy1 * wz1,
        wx1 * wy0 * wz0, wx1 * wy0 * wz1,
        wx1 * wy1 * wz0, wx1 * wy1 * wz1
    };

    long long base = ((long long)cx * RES + cy) * RES + cz;
    const long long R2 = (long long)RES * RES;
    const long long offs[8] = { 0, 1, RES, RES + 1, R2, R2 + 1, R2 + RES, R2 + RES + 1 };

    float4 acc0 = make_float4(0.f, 0.f, 0.f, 0.f);
    float4 acc1 = acc0, acc2 = acc0, acc3 = acc0;

#pragma unroll
    for (int c = 0; c < 8; ++c) {
        const float4* p = (const float4*)(field + (base + offs[c]) * FEAT);
        float4 f0 = p[0];
        float4 f1 = p[1];
        float4 f2 = p[2];
        float4 f3 = p[3];
        float wc = w[c];
        fma4(acc0, wc, f0);
        fma4(acc1, wc, f1);
        fma4(acc2, wc, f2);
        fma4(acc3, wc, f3);
    }

    float4* o = (float4*)(out + (long long)q * FEAT);
    o[0] = acc0;
    o[1] = acc1;
    o[2] = acc2;
    o[3] = acc3;
}

extern "C" void kernel_launch(void* const* d_in, const int* in_sizes, int n_in,
                              void* d_out, int out_size, void* d_ws, size_t ws_size,
                              hipStream_t stream) {
    const float* xyz   = (const float*)d_in[0];
    const float* field = (const float*)d_in[1];
    float* out = (float*)d_out;

    const size_t hist_bytes   = (size_t)NBUCK * 4;
    const size_t sorted_off   = 65536;  // aligned past histogram
    const size_t needed       = sorted_off + (size_t)NQ * 16;

    int blocks = (NQ + 255) / 256;

    if (ws_size < needed) {
        tetra_interp_kernel<<<blocks, 256, 0, stream>>>(xyz, field, out);
        return;
    }

    unsigned int* hist  = (unsigned int*)d_ws;
    float4* sorted      = (float4*)((char*)d_ws + sorted_off);

    hipMemsetAsync(d_ws, 0, hist_bytes, stream);
    hist_kernel<<<blocks, 256, 0, stream>>>(xyz, hist);
    scan_kernel<<<1, 1024, 0, stream>>>(hist);
    scatter_kernel<<<blocks, 256, 0, stream>>>(xyz, hist, sorted);
    interp_sorted_kernel<<<blocks, 256, 0, stream>>>(sorted, field, out);
}

// Round 3
// 146.102 us; speedup vs baseline: 1.2201x; 1.2201x over previous
//
#include <hip/hip_runtime.h>

#define RES 128
#define FEAT 16
#define NQ 1000000
#define NBUCK (128 * 128)   // bucket key = (cx<<7) | cy

__device__ __forceinline__ void fma4(float4& a, float w, const float4& f) {
    a.x = fmaf(w, f.x, a.x);
    a.y = fmaf(w, f.y, a.y);
    a.z = fmaf(w, f.z, a.z);
    a.w = fmaf(w, f.w, a.w);
}

__device__ __forceinline__ int cell_coord(float v) {
    int c = (int)floorf(v * 127.0f);
    return min(max(c, 0), RES - 2);
}

// ---- Pass 1: histogram of bucket keys -------------------------------------
__global__ __launch_bounds__(256) void hist_kernel(
    const float* __restrict__ xyz, unsigned int* __restrict__ hist)
{
    int q = blockIdx.x * blockDim.x + threadIdx.x;
    if (q >= NQ) return;
    int cx = cell_coord(xyz[3 * q + 0]);
    int cy = cell_coord(xyz[3 * q + 1]);
    atomicAdd(&hist[(cx << 7) | cy], 1u);
}

// ---- Pass 2: exclusive scan over 16384 counters (single block) ------------
__global__ __launch_bounds__(1024) void scan_kernel(unsigned int* __restrict__ hist)
{
    __shared__ unsigned int partial[1024];
    int t = threadIdx.x;
    unsigned int vals[16];
    unsigned int sum = 0;
#pragma unroll
    for (int i = 0; i < 16; ++i) { vals[i] = hist[t * 16 + i]; sum += vals[i]; }
    partial[t] = sum;
    __syncthreads();
    for (int off = 1; off < 1024; off <<= 1) {
        unsigned int v = (t >= off) ? partial[t - off] : 0u;
        __syncthreads();
        partial[t] += v;
        __syncthreads();
    }
    unsigned int excl = (t == 0) ? 0u : partial[t - 1];
#pragma unroll
    for (int i = 0; i < 16; ++i) { unsigned int v = vals[i]; hist[t * 16 + i] = excl; excl += v; }
}

// ---- Pass 3: scatter queries into bucket order ----------------------------
__global__ __launch_bounds__(256) void scatter_kernel(
    const float* __restrict__ xyz, unsigned int* __restrict__ cursor,
    float4* __restrict__ sorted)
{
    int q = blockIdx.x * blockDim.x + threadIdx.x;
    if (q >= NQ) return;
    float x = xyz[3 * q + 0];
    float y = xyz[3 * q + 1];
    float z = xyz[3 * q + 2];
    int cx = cell_coord(x);
    int cy = cell_coord(y);
    unsigned int pos = atomicAdd(&cursor[(cx << 7) | cy], 1u);
    sorted[pos] = make_float4(x, y, z, __int_as_float(q));
}

// ---- Pass 4: interpolate, 4 lanes per query -------------------------------
// Lane group of 4 handles one query; lane l loads float4 #l of each corner
// row, so the 4 lanes' 16B accesses coalesce into ONE 64B-line transaction
// per corner per query (4x fewer gather transactions than 1-thread/query).
__global__ __launch_bounds__(256) void interp_sorted4_kernel(
    const float4* __restrict__ sorted,
    const float* __restrict__ field,
    float* __restrict__ out)
{
    // bijective XCD-aware swizzle: contiguous sorted chunk per XCD L2
    int nwg = gridDim.x;
    int qn = nwg >> 3, r = nwg & 7;
    int xcd = blockIdx.x & 7, i = blockIdx.x >> 3;
    int wg = (xcd < r ? xcd * (qn + 1) : r * (qn + 1) + (xcd - r) * qn) + i;

    int t = wg * blockDim.x + threadIdx.x;
    int q = t >> 2;          // query index
    int l = t & 3;           // float4 slot within the 16-float row
    if (q >= NQ) return;

    float4 s = sorted[q];    // same addr for the 4 lanes -> broadcast
    float x = s.x, y = s.y, z = s.z;
    int oidx = __float_as_int(s.w);

    const float scale = 127.0f;
    const float h = 1.0f / 127.0f;

    int cx = cell_coord(x);
    int cy = cell_coord(y);
    int cz = cell_coord(z);

    float tx = (x - (float)cx * h) * scale;
    float ty = (y - (float)cy * h) * scale;
    float tz = (z - (float)cz * h) * scale;

    float wx0 = 1.0f - tx, wx1 = tx;
    float wy0 = 1.0f - ty, wy1 = ty;
    float wz0 = 1.0f - tz, wz1 = tz;

    float w[8] = {
        wx0 * wy0 * wz0, wx0 * wy0 * wz1,
        wx0 * wy1 * wz0, wx0 * wy1 * wz1,
        wx1 * wy0 * wz0, wx1 * wy0 * wz1,
        wx1 * wy1 * wz0, wx1 * wy1 * wz1
    };

    long long base = ((long long)cx * RES + cy) * RES + cz;
    const long long R2 = (long long)RES * RES;
    const long long offs[8] = { 0, 1, RES, RES + 1, R2, R2 + 1, R2 + RES, R2 + RES + 1 };

    float4 acc = make_float4(0.f, 0.f, 0.f, 0.f);

#pragma unroll
    for (int c = 0; c < 8; ++c) {
        const float4* p = (const float4*)(field + (base + offs[c]) * FEAT) + l;
        float4 f = *p;
        fma4(acc, w[c], f);
    }

    ((float4*)out)[(long long)oidx * 4 + l] = acc;
}

// ---- Fallback (round-1 direct kernel) -------------------------------------
__global__ __launch_bounds__(256) void tetra_interp_kernel(
    const float* __restrict__ xyz,
    const float* __restrict__ field,
    float* __restrict__ out)
{
    int q = blockIdx.x * blockDim.x + threadIdx.x;
    if (q >= NQ) return;

    float x = xyz[q * 3 + 0];
    float y = xyz[q * 3 + 1];
    float z = xyz[q * 3 + 2];

    const float scale = 127.0f;
    const float h = 1.0f / 127.0f;

    int cx = cell_coord(x);
    int cy = cell_coord(y);
    int cz = cell_coord(z);

    float tx = (x - (float)cx * h) * scale;
    float ty = (y - (float)cy * h) * scale;
    float tz = (z - (float)cz * h) * scale;

    float wx0 = 1.0f - tx, wx1 = tx;
    float wy0 = 1.0f - ty, wy1 = ty;
    float wz0 = 1.0f - tz, wz1 = tz;

    float w[8] = {
        wx0 * wy0 * wz0, wx0 * wy0 * wz1,
        wx0 * wy1 * wz0, wx0 * wy1 * wz1,
        wx1 * wy0 * wz0, wx1 * wy0 * wz1,
        wx1 * wy1 * wz0, wx1 * wy1 * wz1
    };

    long long base = ((long long)cx * RES + cy) * RES + cz;
    const long long R2 = (long long)RES * RES;
    const long long offs[8] = { 0, 1, RES, RES + 1, R2, R2 + 1, R2 + RES, R2 + RES + 1 };

    float4 acc0 = make_float4(0.f, 0.f, 0.f, 0.f);
    float4 acc1 = acc0, acc2 = acc0, acc3 = acc0;

#pragma unroll
    for (int c = 0; c < 8; ++c) {
        const float4* p = (const float4*)(field + (base + offs[c]) * FEAT);
        float4 f0 = p[0];
        float4 f1 = p[1];
        float4 f2 = p[2];
        float4 f3 = p[3];
        float wc = w[c];
        fma4(acc0, wc, f0);
        fma4(acc1, wc, f1);
        fma4(acc2, wc, f2);
        fma4(acc3, wc, f3);
    }

    float4* o = (float4*)(out + (long long)q * FEAT);
    o[0] = acc0;
    o[1] = acc1;
    o[2] = acc2;
    o[3] = acc3;
}

extern "C" void kernel_launch(void* const* d_in, const int* in_sizes, int n_in,
                              void* d_out, int out_size, void* d_ws, size_t ws_size,
                              hipStream_t stream) {
    const float* xyz   = (const float*)d_in[0];
    const float* field = (const float*)d_in[1];
    float* out = (float*)d_out;

    const size_t sorted_off = 65536;  // aligned past histogram
    const size_t needed     = sorted_off + (size_t)NQ * 16;

    int blocks = (NQ + 255) / 256;

    if (ws_size < needed) {
        tetra_interp_kernel<<<blocks, 256, 0, stream>>>(xyz, field, out);
        return;
    }

    unsigned int* hist  = (unsigned int*)d_ws;
    float4* sorted      = (float4*)((char*)d_ws + sorted_off);

    hipMemsetAsync(d_ws, 0, (size_t)NBUCK * 4, stream);
    hist_kernel<<<blocks, 256, 0, stream>>>(xyz, hist);
    scan_kernel<<<1, 1024, 0, stream>>>(hist);
    scatter_kernel<<<blocks, 256, 0, stream>>>(xyz, hist, sorted);

    int iblocks = (NQ * 4 + 255) / 256;   // 4 lanes per query
    interp_sorted4_kernel<<<iblocks, 256, 0, stream>>>(sorted, field, out);
}